// Round 15
// baseline (4627.774 us; speedup 1.0000x reference)
//
#include <hip/hip_runtime.h>

typedef _Float16 f16;
typedef _Float16 h2 __attribute__((ext_vector_type(2)));
typedef _Float16 h8 __attribute__((ext_vector_type(8)));
typedef float f4 __attribute__((ext_vector_type(4)));

constexpr int Bb = 64, Tt = 2048, Xx = 128, Hh = 256, G4 = 1024, Z2 = 128;

__device__ __forceinline__ float fdot2f(h2 a, h2 b, float c) {
#if __has_builtin(__builtin_amdgcn_fdot2)
  return __builtin_amdgcn_fdot2(a, b, c, false);
#else
  return c + (float)a[0] * (float)b[0] + (float)a[1] * (float)b[1];
#endif
}
__device__ __forceinline__ float tanhf_(float x) {
  float e = __expf(2.0f * x);
  return 1.0f - 2.0f * __builtin_amdgcn_rcpf(e + 1.0f);
}
__device__ __forceinline__ h2 bch2(unsigned int u) { return __builtin_bit_cast(h2, u); }

template <int CTRL>
__device__ __forceinline__ float qb(float v) {  // quad_perm shuffle
  return __builtin_bit_cast(float,
      __builtin_amdgcn_mov_dpp(__builtin_bit_cast(int, v), CTRL, 0xf, 0xf, true));
}

// ---------------- casts ----------------
__global__ void cast_f16_k(const float* __restrict__ in, f16* __restrict__ out, int n) {
  int i = (blockIdx.x * 256 + threadIdx.x) * 4;
  if (i >= n) return;
  float4 v = *(const float4*)(in + i);
  h2 a = {(f16)v.x, (f16)v.y};
  h2 b = {(f16)v.z, (f16)v.w};
  uint2 o = {__builtin_bit_cast(unsigned int, a), __builtin_bit_cast(unsigned int, b)};
  *(uint2*)(out + i) = o;
}

// Wi columns permuted to quad-gate order col' = 4j+g (orig col = g*256+j):
// xp then holds the 4 gate pre-activations of unit j contiguously.
__global__ void cast_wiP_k(const float* __restrict__ Wi, f16* __restrict__ out) {
  int idx = blockIdx.x * 256 + threadIdx.x;  // 131072 = 128*1024
  int k = idx >> 10, cp = idx & 1023;
  out[idx] = (f16)Wi[(long)k * G4 + (cp & 3) * 256 + (cp >> 2)];
}
__global__ void cast_bhp_k(const float* __restrict__ bh, float* __restrict__ bhp) {
  int cp = blockIdx.x * 256 + threadIdx.x;   // 1024
  bhp[cp] = bh[(cp & 3) * 256 + (cp >> 2)];
}

// v512-layout (control): thread tid owns packed cols c0=2tid, c1=2tid+1
// (cc -> gate cc&3, unit cc>>2).
__global__ void cast_whT2_k(const float* __restrict__ Wh, f16* __restrict__ WhT2) {
  int idx = blockIdx.x * 256 + threadIdx.x;  // 262144 = 512 threads * 512 f16
  int tid = idx >> 9, f = idx & 511;
  int s = f >> 1, e = f & 1;
  int c_off, k;
  if (s < 96)      { c_off = 0; k = 2 * s + e; }
  else if (s < 192){ c_off = 1; k = 2 * (s - 96) + e; }
  else if (s < 224){ c_off = 0; k = 192 + 2 * (s - 192) + e; }
  else             { c_off = 1; k = 192 + 2 * (s - 224) + e; }
  int cc = 2 * tid + c_off;
  int j = cc >> 2, g = cc & 3;
  WhT2[(long)tid * 512 + f] = (f16)Wh[(long)k * G4 + g * 256 + j];
}

// v256-layout: thread tid owns ALL 4 gates of unit j=tid (1024 f16).
// h2 slot s = i*16 + g*4 + m (h-group i 0..31, gate g, h2 m) -> k = 8i+2m+e.
// i<24 (384 h2) -> registers; i in [24,32) (128 h2) -> LDS tail.
__global__ void cast_whT6_k(const float* __restrict__ Wh, f16* __restrict__ WhT6) {
  int idx = blockIdx.x * 256 + threadIdx.x;  // 262144 = 256 threads * 1024 f16
  int tid = idx >> 10, f = idx & 1023;
  int s = f >> 1, e = f & 1;
  int i = s >> 4, g = (s >> 2) & 3, m = s & 3;
  int k = 8 * i + 2 * m + e;
  WhT6[idx] = (f16)Wh[(long)k * G4 + g * 256 + tid];
}

// ---------------- generic f16 MFMA GEMM, 64x64 tile ----------------
__global__ __launch_bounds__(256, 4) void gemm_f16_k(
    const f16* __restrict__ A, const f16* __restrict__ Bm, const float* __restrict__ bias,
    f16* __restrict__ C16, float* __restrict__ Cmu, float* __restrict__ Cls,
    int N, int K, int a_shift, int a_ostride, int a_t0,
    int mode, int o_t0, int tcshift)
{
  __shared__ __align__(16) f16 At[64][48];
  __shared__ __align__(16) f16 Bt[64][48];
  const int tid = threadIdx.x;
  const int mblk = blockIdx.x, nblk = blockIdx.y;
  const int w = tid >> 6, lane = tid & 63;

  const int sa_row = tid >> 2, sa_k = (tid & 3) * 8;
  const int m_g = mblk * 64 + sa_row;
  const long arow = (long)(m_g >> a_shift) * a_ostride + a_t0 + (m_g & ((1 << a_shift) - 1));
  const f16* aptr = A + arow * K + sa_k;
  const int sb_k = tid >> 3, sb_n = (tid & 7) * 8;
  const f16* bptr = Bm + (long)sb_k * N + nblk * 64 + sb_n;

  f4 acc[4];
#pragma unroll
  for (int i = 0; i < 4; ++i) acc[i] = (f4){0.f, 0.f, 0.f, 0.f};

  const int arow_l = w * 16 + (lane & 15);
  const int k0 = (lane >> 4) * 8;

  for (int kk = 0; kk < K; kk += 32) {
    uint4 av = *(const uint4*)(aptr + kk);
    uint4 bv = *(const uint4*)(bptr + (long)kk * N);
    __syncthreads();
    *(uint4*)&At[sa_row][sa_k] = av;
    h8 bx = __builtin_bit_cast(h8, bv);
#pragma unroll
    for (int j = 0; j < 8; ++j) Bt[sb_n + j][sb_k] = bx[j];
    __syncthreads();
    h8 af = *(const h8*)&At[arow_l][k0];
#pragma unroll
    for (int nt = 0; nt < 4; ++nt) {
      h8 bf = *(const h8*)&Bt[nt * 16 + (lane & 15)][k0];
      acc[nt] = __builtin_amdgcn_mfma_f32_16x16x32_f16(af, bf, acc[nt], 0, 0, 0);
    }
  }

  const int row_l = w * 16 + ((lane >> 4) << 2);
  const int col_l = lane & 15;
#pragma unroll
  for (int nt = 0; nt < 4; ++nt) {
    int gcol = nblk * 64 + nt * 16 + col_l;
    float bv = bias[gcol];
#pragma unroll
    for (int r = 0; r < 4; ++r) {
      int gm = mblk * 64 + row_l + r;
      float val = acc[nt][r] + bv;
      if (mode == 1) val = fmaxf(val, 0.f);
      if (mode <= 1) {
        C16[(long)gm * N + gcol] = (f16)val;
      } else {
        int bb = gm >> tcshift, tl = gm & ((1 << tcshift) - 1);
        long orow = (long)bb * Tt + o_t0 + tl;
        if (gcol < 64) Cmu[orow * 64 + gcol] = val;
        else Cls[orow * 64 + (gcol - 64)] = val;
      }
    }
  }
}

// ---------------- v256 scan: 1 wave/SIMD, thread-owns-unit (chunk 0) --------
// 256 threads = 4 waves = 1 wave/SIMD -> 512-unified-reg budget per wave.
// Thread tid owns all 4 gates of unit j=tid: 512 fdot2/step, ZERO cross-lane
// exchange (no dpp, activations/c/h all thread-local). h broadcast reads are
// amortized 4x (32 b128 serve 4 gates). Weights: 384 h2 in regs + 128 h2 in
// a 128 KB LDS tail (32 per-lane b128 reads/step, conflict-free).
__global__ void __launch_bounds__(256, 1) lstm256_k(
    const f16* __restrict__ WhT6, const f16* __restrict__ xp,
    f16* __restrict__ hout, float* __restrict__ c_state, f16* __restrict__ h_state,
    int TC, int first)
{
  const int b = blockIdx.x, tid = threadIdx.x;
  __shared__ __align__(16) h2 hbuf[2][128];   // double-buffered h_t (1 KB)
  __shared__ uint4 wt[32][256];               // weight tail i in [24,32): 128 KB

  h2 w[384];
  {
    const uint4* p4 = (const uint4*)(WhT6 + (long)tid * 1024);
#pragma unroll
    for (int u = 0; u < 96; ++u) {
      uint4 v = p4[u];
      w[4 * u + 0] = bch2(v.x); w[4 * u + 1] = bch2(v.y);
      w[4 * u + 2] = bch2(v.z); w[4 * u + 3] = bch2(v.w);
    }
#pragma unroll
    for (int r = 0; r < 32; ++r) wt[r][tid] = p4[96 + r];
  }

  float c = first ? 0.f : c_state[b * Hh + tid];
  if (tid < 128) {
    h2 hz = {(f16)0.f, (f16)0.f};
    hbuf[0][tid] = first ? hz : ((const h2*)h_state)[b * 128 + tid];
  }
  __syncthreads();

  const f16* xptr = xp + (long)b * TC * G4 + 4 * tid;   // quad-gate xp order
  const f16* xend = xptr + (long)(TC - 1) * G4;
  uint2 xv = *(const uint2*)xptr;
  int p = 0;
  for (int t = 0; t < TC; ++t) {
    const f16* xnp = (xptr == xend) ? xptr : xptr + G4;
    uint2 xn = *(const uint2*)xnp;

    float d0 = 0.f, d1 = 0.f, d2 = 0.f, d3 = 0.f;
    const uint4* hb4 = (const uint4*)&hbuf[p][0];
#pragma unroll
    for (int ii = 0; ii < 24; ++ii) {                   // register head
      uint4 hv = hb4[ii];
      h2 h0 = bch2(hv.x), h1 = bch2(hv.y), h2_ = bch2(hv.z), h3 = bch2(hv.w);
      d0 = fdot2f(w[16 * ii + 0], h0, d0);  d0 = fdot2f(w[16 * ii + 1], h1, d0);
      d0 = fdot2f(w[16 * ii + 2], h2_, d0); d0 = fdot2f(w[16 * ii + 3], h3, d0);
      d1 = fdot2f(w[16 * ii + 4], h0, d1);  d1 = fdot2f(w[16 * ii + 5], h1, d1);
      d1 = fdot2f(w[16 * ii + 6], h2_, d1); d1 = fdot2f(w[16 * ii + 7], h3, d1);
      d2 = fdot2f(w[16 * ii + 8], h0, d2);  d2 = fdot2f(w[16 * ii + 9], h1, d2);
      d2 = fdot2f(w[16 * ii + 10], h2_, d2); d2 = fdot2f(w[16 * ii + 11], h3, d2);
      d3 = fdot2f(w[16 * ii + 12], h0, d3);  d3 = fdot2f(w[16 * ii + 13], h1, d3);
      d3 = fdot2f(w[16 * ii + 14], h2_, d3); d3 = fdot2f(w[16 * ii + 15], h3, d3);
    }
#pragma unroll
    for (int ii = 24; ii < 32; ++ii) {                  // LDS tail
      uint4 hv = hb4[ii];
      h2 h0 = bch2(hv.x), h1 = bch2(hv.y), h2_ = bch2(hv.z), h3 = bch2(hv.w);
      uint4 w0 = wt[(ii - 24) * 4 + 0][tid];
      uint4 w1 = wt[(ii - 24) * 4 + 1][tid];
      uint4 w2 = wt[(ii - 24) * 4 + 2][tid];
      uint4 w3 = wt[(ii - 24) * 4 + 3][tid];
      d0 = fdot2f(bch2(w0.x), h0, d0); d0 = fdot2f(bch2(w0.y), h1, d0);
      d0 = fdot2f(bch2(w0.z), h2_, d0); d0 = fdot2f(bch2(w0.w), h3, d0);
      d1 = fdot2f(bch2(w1.x), h0, d1); d1 = fdot2f(bch2(w1.y), h1, d1);
      d1 = fdot2f(bch2(w1.z), h2_, d1); d1 = fdot2f(bch2(w1.w), h3, d1);
      d2 = fdot2f(bch2(w2.x), h0, d2); d2 = fdot2f(bch2(w2.y), h1, d2);
      d2 = fdot2f(bch2(w2.z), h2_, d2); d2 = fdot2f(bch2(w2.w), h3, d2);
      d3 = fdot2f(bch2(w3.x), h0, d3); d3 = fdot2f(bch2(w3.y), h1, d3);
      d3 = fdot2f(bch2(w3.z), h2_, d3); d3 = fdot2f(bch2(w3.w), h3, d3);
    }

    h2 xlo = bch2(xv.x), xhi = bch2(xv.y);
    float ti = d0 + (float)xlo[0], tf = d1 + (float)xlo[1];
    float tg = d2 + (float)xhi[0], to = d3 + (float)xhi[1];
    float ai = __builtin_amdgcn_rcpf(1.0f + __expf(-ti));
    float af = __builtin_amdgcn_rcpf(1.0f + __expf(-tf));
    float ag = 1.0f - 2.0f * __builtin_amdgcn_rcpf(1.0f + __expf(2.0f * tg));
    float ao = __builtin_amdgcn_rcpf(1.0f + __expf(-to));
    c = af * c + ai * ag;
    float hval = ao * tanhf_(c);
    f16 hh = (f16)hval;
    ((f16*)&hbuf[p ^ 1][0])[tid] = hh;
    hout[((long)b * TC + t) * Hh + tid] = hh;
    __syncthreads();
    p ^= 1;
    xv = xn;
    xptr = xnp;
  }
  c_state[b * Hh + tid] = c;
  if (tid < 128) ((h2*)h_state)[b * 128 + tid] = hbuf[p][tid];
}

// ---------------- v512 scan (control, ~1447 us; x-load adapted to quad-xp) --
__global__ void __launch_bounds__(512, 2) lstm512_k(
    const f16* __restrict__ WhT2, const f16* __restrict__ xp,
    f16* __restrict__ hout, float* __restrict__ c_state, f16* __restrict__ h_state,
    int TC, int first)
{
  const int b = blockIdx.x, tid = threadIdx.x;
  const int j = tid >> 1, odd = tid & 1;
  __shared__ __align__(16) h2 hbuf[2][128];
  __shared__ uint4 wt[16][512];

  h2 w[192];
  {
    const uint4* p4 = (const uint4*)(WhT2 + (long)tid * 512);
#pragma unroll
    for (int u = 0; u < 48; ++u) {
      uint4 v = p4[u];
      w[4 * u + 0] = bch2(v.x); w[4 * u + 1] = bch2(v.y);
      w[4 * u + 2] = bch2(v.z); w[4 * u + 3] = bch2(v.w);
    }
#pragma unroll
    for (int gg = 0; gg < 16; ++gg) wt[gg][tid] = p4[48 + gg];
  }

  float c = first ? 0.f : c_state[b * Hh + j];
  if (tid < 128) {
    h2 hz = {(f16)0.f, (f16)0.f};
    hbuf[0][tid] = first ? hz : ((const h2*)h_state)[b * 128 + tid];
  }
  __syncthreads();

  const float sgn0 = odd ? 2.0f : -1.0f;
  // quad-gate xp: this thread's 2 pre-activations are contiguous at 2*tid.
  const f16* xptr = xp + (long)b * TC * G4 + 2 * tid;
  const f16* xend = xptr + (long)(TC - 1) * G4;
  h2 xv = *(const h2*)xptr;
  int p = 0;
  for (int t = 0; t < TC; ++t) {
    const f16* xnp = (xptr == xend) ? xptr : xptr + G4;
    h2 xn = *(const h2*)xnp;

    float a0 = (float)xv[0], b0 = 0.f, a1 = (float)xv[1], b1 = 0.f;
    const uint4* hb4 = (const uint4*)&hbuf[p][0];
#pragma unroll
    for (int i = 0; i < 24; ++i) {
      uint4 hv = hb4[i];
      a0 = fdot2f(w[4 * i + 0], bch2(hv.x), a0);
      b0 = fdot2f(w[4 * i + 1], bch2(hv.y), b0);
      a0 = fdot2f(w[4 * i + 2], bch2(hv.z), a0);
      b0 = fdot2f(w[4 * i + 3], bch2(hv.w), b0);
      a1 = fdot2f(w[96 + 4 * i + 0], bch2(hv.x), a1);
      b1 = fdot2f(w[96 + 4 * i + 1], bch2(hv.y), b1);
      a1 = fdot2f(w[96 + 4 * i + 2], bch2(hv.z), a1);
      b1 = fdot2f(w[96 + 4 * i + 3], bch2(hv.w), b1);
    }
#pragma unroll
    for (int gg = 0; gg < 8; ++gg) {
      uint4 hv = hb4[24 + gg];
      uint4 wa = wt[gg][tid];
      uint4 wb = wt[8 + gg][tid];
      a0 = fdot2f(bch2(wa.x), bch2(hv.x), a0);
      b0 = fdot2f(bch2(wa.y), bch2(hv.y), b0);
      a0 = fdot2f(bch2(wa.z), bch2(hv.z), a0);
      b0 = fdot2f(bch2(wa.w), bch2(hv.w), b0);
      a1 = fdot2f(bch2(wb.x), bch2(hv.x), a1);
      b1 = fdot2f(bch2(wb.y), bch2(hv.y), b1);
      a1 = fdot2f(bch2(wb.z), bch2(hv.z), a1);
      b1 = fdot2f(bch2(wb.w), bch2(hv.w), b1);
    }
    float A0 = a0 + b0, A1 = a1 + b1;

    float e0 = __expf(sgn0 * A0);
    float r0 = __builtin_amdgcn_rcpf(1.0f + e0);
    float act0 = odd ? 1.0f - 2.0f * r0 : r0;
    float e1 = __expf(-A1);
    float act1 = __builtin_amdgcn_rcpf(1.0f + e1);

    float px0 = qb<0xB1>(act0), px1 = qb<0xB1>(act1);
    float ai = odd ? px0 : act0;
    float af = odd ? px1 : act1;
    float ag = odd ? act0 : px0;
    float ao = odd ? act1 : px1;
    c = af * c + ai * ag;
    float hval = ao * tanhf_(c);
    if (!odd) {
      f16 hh = (f16)hval;
      ((f16*)&hbuf[p ^ 1][0])[j] = hh;
      hout[((long)b * TC + t) * Hh + j] = hh;
    }
    __syncthreads();
    p ^= 1;
    xv = xn;
    xptr = xnp;
  }
  if (!odd) c_state[b * Hh + j] = c;
  if (tid < 128) ((h2*)h_state)[b * 128 + tid] = hbuf[p][tid];
}

// ---------------- host ----------------
extern "C" void kernel_launch(void* const* d_in, const int* in_sizes, int n_in,
                              void* d_out, int out_size, void* d_ws, size_t ws_size,
                              hipStream_t stream)
{
  const float* x  = (const float*)d_in[0];
  const float* Wi = (const float*)d_in[1];
  const float* Wh = (const float*)d_in[2];
  const float* bh = (const float*)d_in[3];
  const float* W1 = (const float*)d_in[4];
  const float* b1 = (const float*)d_in[5];
  const float* W2 = (const float*)d_in[6];
  const float* b2 = (const float*)d_in[7];
  float* out = (float*)d_out;

  char* ws = (char*)d_ws;
  size_t off = 0;
  auto alloc = [&](size_t bytes) -> char* {
    char* p = ws + off;
    off = (off + bytes + 255) & ~(size_t)255;
    return p;
  };
  f16* x16    = (f16*)alloc((size_t)Bb * Tt * Xx * 2);
  f16* wi16p  = (f16*)alloc((size_t)Xx * G4 * 2);
  float* bhp  = (float*)alloc((size_t)G4 * 4);
  f16* whT2   = (f16*)alloc((size_t)G4 * Hh * 2);
  f16* whT6   = (f16*)alloc((size_t)G4 * Hh * 2);
  f16* w116   = (f16*)alloc((size_t)Hh * Hh * 2);
  f16* w216   = (f16*)alloc((size_t)Hh * Z2 * 2);
  float* cst  = (float*)alloc((size_t)Bb * Hh * 4);
  f16* hst    = (f16*)alloc((size_t)Bb * Hh * 2);

  int tc = 1024;  // 2 chunks: chunk0 = 1-wave/SIMD experiment, chunk1 = control
  while (tc > 32) {
    size_t need = (size_t)Bb * tc * G4 * 2 + (size_t)Bb * tc * Hh * 2;
    if (off + need <= ws_size) break;
    tc >>= 1;
  }
  int tcsh = __builtin_ctz((unsigned)tc);
  f16* xp16 = (f16*)alloc((size_t)Bb * tc * G4 * 2);
  f16* h16  = (f16*)alloc((size_t)Bb * tc * Hh * 2);
  f16* hid16 = xp16;  // head hidden aliases xp (xp fully consumed by the scan)

  cast_f16_k<<<(Bb * Tt * Xx) / 1024, 256, 0, stream>>>(x, x16, Bb * Tt * Xx);
  cast_wiP_k<<<(Xx * G4) / 256, 256, 0, stream>>>(Wi, wi16p);
  cast_bhp_k<<<4, 256, 0, stream>>>(bh, bhp);
  cast_f16_k<<<(Hh * Hh) / 1024, 256, 0, stream>>>(W1, w116, Hh * Hh);
  cast_f16_k<<<(Hh * Z2) / 1024, 256, 0, stream>>>(W2, w216, Hh * Z2);
  cast_whT2_k<<<(Hh * G4) / 256, 256, 0, stream>>>(Wh, whT2);
  cast_whT6_k<<<(Hh * G4) / 256, 256, 0, stream>>>(Wh, whT6);

  float* mu = out;
  float* ls = out + (size_t)Bb * Tt * 64;

  int ci = 0;
  for (int t0 = 0; t0 < Tt; t0 += tc, ++ci) {
    dim3 gx(Bb * tc / 64, G4 / 64);
    gemm_f16_k<<<gx, 256, 0, stream>>>(x16, wi16p, bhp, xp16, nullptr, nullptr,
                                       G4, Xx, tcsh, Tt, t0, 0, 0, 0);
    if (ci == 0)
      lstm256_k<<<Bb, 256, 0, stream>>>(whT6, xp16, h16, cst, hst, tc, (t0 == 0) ? 1 : 0);
    else
      lstm512_k<<<Bb, 512, 0, stream>>>(whT2, xp16, h16, cst, hst, tc, (t0 == 0) ? 1 : 0);
    dim3 g1g(Bb * tc / 64, Hh / 64);
    gemm_f16_k<<<g1g, 256, 0, stream>>>(h16, w116, b1, hid16, nullptr, nullptr,
                                        Hh, Hh, 30, 0, 0, 1, 0, 0);
    dim3 g2g(Bb * tc / 64, Z2 / 64);
    gemm_f16_k<<<g2g, 256, 0, stream>>>(hid16, w216, b2, nullptr, mu, ls,
                                        Z2, Hh, 30, 0, 0, 2, t0, tcsh);
  }
}

// Round 16
// 3132.011 us; speedup vs baseline: 1.4776x; 1.4776x over previous
//
#include <hip/hip_runtime.h>

typedef _Float16 f16;
typedef _Float16 h2 __attribute__((ext_vector_type(2)));
typedef _Float16 h8 __attribute__((ext_vector_type(8)));
typedef float f4 __attribute__((ext_vector_type(4)));

constexpr int Bb = 64, Tt = 2048, Xx = 128, Hh = 256, G4 = 1024, Z2 = 128;

__device__ __forceinline__ float fdot2f(h2 a, h2 b, float c) {
#if __has_builtin(__builtin_amdgcn_fdot2)
  return __builtin_amdgcn_fdot2(a, b, c, false);
#else
  return c + (float)a[0] * (float)b[0] + (float)a[1] * (float)b[1];
#endif
}
__device__ __forceinline__ float tanhf_(float x) {
  float e = __expf(2.0f * x);
  return 1.0f - 2.0f * __builtin_amdgcn_rcpf(e + 1.0f);
}
__device__ __forceinline__ h2 bch2(unsigned int u) { return __builtin_bit_cast(h2, u); }

template <int CTRL>
__device__ __forceinline__ float qb(float v) {  // quad_perm shuffle
  return __builtin_bit_cast(float,
      __builtin_amdgcn_mov_dpp(__builtin_bit_cast(int, v), CTRL, 0xf, 0xf, true));
}

// ---------------- casts ----------------
__global__ void cast_f16_k(const float* __restrict__ in, f16* __restrict__ out, int n) {
  int i = (blockIdx.x * 256 + threadIdx.x) * 4;
  if (i >= n) return;
  float4 v = *(const float4*)(in + i);
  h2 a = {(f16)v.x, (f16)v.y};
  h2 b = {(f16)v.z, (f16)v.w};
  uint2 o = {__builtin_bit_cast(unsigned int, a), __builtin_bit_cast(unsigned int, b)};
  *(uint2*)(out + i) = o;
}

// Wi columns permuted to quad-gate order col' = 4j+g (orig col = g*256+j).
__global__ void cast_wiP_k(const float* __restrict__ Wi, f16* __restrict__ out) {
  int idx = blockIdx.x * 256 + threadIdx.x;  // 131072 = 128*1024
  int k = idx >> 10, cp = idx & 1023;
  out[idx] = (f16)Wi[(long)k * G4 + (cp & 3) * 256 + (cp >> 2)];
}
__global__ void cast_bhp_k(const float* __restrict__ bh, float* __restrict__ bhp) {
  int cp = blockIdx.x * 256 + threadIdx.x;   // 1024
  bhp[cp] = bh[(cp & 3) * 256 + (cp >> 2)];
}

// v512-layout (control): thread tid owns packed cols c0=2tid, c1=2tid+1.
__global__ void cast_whT2_k(const float* __restrict__ Wh, f16* __restrict__ WhT2) {
  int idx = blockIdx.x * 256 + threadIdx.x;  // 262144 = 512 threads * 512 f16
  int tid = idx >> 9, f = idx & 511;
  int s = f >> 1, e = f & 1;
  int c_off, k;
  if (s < 96)      { c_off = 0; k = 2 * s + e; }
  else if (s < 192){ c_off = 1; k = 2 * (s - 96) + e; }
  else if (s < 224){ c_off = 0; k = 192 + 2 * (s - 192) + e; }
  else             { c_off = 1; k = 192 + 2 * (s - 224) + e; }
  int cc = 2 * tid + c_off;
  int j = cc >> 2, g = cc & 3;
  WhT2[(long)tid * 512 + f] = (f16)Wh[(long)k * G4 + g * 256 + j];
}

// split-layout: stream (hb, tid) of 256 f16 = column col = 4*(hb*128 + (tid>>2))
// + (tid&3) over K=0..255 linearly. k<192 -> 96 reg h2; k>=192 -> LDS tail.
__global__ void cast_whQ_k(const float* __restrict__ Wh, f16* __restrict__ Wq) {
  int idx = blockIdx.x * 256 + threadIdx.x;  // 262144 = 1024 streams * 256 f16
  int st = idx >> 8, k = idx & 255;
  int tid = st & 511, hb = st >> 9;
  int j = hb * 128 + (tid >> 2), g = tid & 3;
  Wq[(long)st * 256 + k] = (f16)Wh[(long)k * G4 + g * 256 + j];
}

// ---------------- generic f16 MFMA GEMM, 64x64 tile ----------------
__global__ __launch_bounds__(256, 4) void gemm_f16_k(
    const f16* __restrict__ A, const f16* __restrict__ Bm, const float* __restrict__ bias,
    f16* __restrict__ C16, float* __restrict__ Cmu, float* __restrict__ Cls,
    int N, int K, int a_shift, int a_ostride, int a_t0,
    int mode, int o_t0, int tcshift)
{
  __shared__ __align__(16) f16 At[64][48];
  __shared__ __align__(16) f16 Bt[64][48];
  const int tid = threadIdx.x;
  const int mblk = blockIdx.x, nblk = blockIdx.y;
  const int w = tid >> 6, lane = tid & 63;

  const int sa_row = tid >> 2, sa_k = (tid & 3) * 8;
  const int m_g = mblk * 64 + sa_row;
  const long arow = (long)(m_g >> a_shift) * a_ostride + a_t0 + (m_g & ((1 << a_shift) - 1));
  const f16* aptr = A + arow * K + sa_k;
  const int sb_k = tid >> 3, sb_n = (tid & 7) * 8;
  const f16* bptr = Bm + (long)sb_k * N + nblk * 64 + sb_n;

  f4 acc[4];
#pragma unroll
  for (int i = 0; i < 4; ++i) acc[i] = (f4){0.f, 0.f, 0.f, 0.f};

  const int arow_l = w * 16 + (lane & 15);
  const int k0 = (lane >> 4) * 8;

  for (int kk = 0; kk < K; kk += 32) {
    uint4 av = *(const uint4*)(aptr + kk);
    uint4 bv = *(const uint4*)(bptr + (long)kk * N);
    __syncthreads();
    *(uint4*)&At[sa_row][sa_k] = av;
    h8 bx = __builtin_bit_cast(h8, bv);
#pragma unroll
    for (int j = 0; j < 8; ++j) Bt[sb_n + j][sb_k] = bx[j];
    __syncthreads();
    h8 af = *(const h8*)&At[arow_l][k0];
#pragma unroll
    for (int nt = 0; nt < 4; ++nt) {
      h8 bf = *(const h8*)&Bt[nt * 16 + (lane & 15)][k0];
      acc[nt] = __builtin_amdgcn_mfma_f32_16x16x32_f16(af, bf, acc[nt], 0, 0, 0);
    }
  }

  const int row_l = w * 16 + ((lane >> 4) << 2);
  const int col_l = lane & 15;
#pragma unroll
  for (int nt = 0; nt < 4; ++nt) {
    int gcol = nblk * 64 + nt * 16 + col_l;
    float bv = bias[gcol];
#pragma unroll
    for (int r = 0; r < 4; ++r) {
      int gm = mblk * 64 + row_l + r;
      float val = acc[nt][r] + bv;
      if (mode == 1) val = fmaxf(val, 0.f);
      if (mode <= 1) {
        C16[(long)gm * N + gcol] = (f16)val;
      } else {
        int bb = gm >> tcshift, tl = gm & ((1 << tcshift) - 1);
        long orow = (long)bb * Tt + o_t0 + tl;
        if (gcol < 64) Cmu[orow * 64 + gcol] = val;
        else Cls[orow * 64 + (gcol - 64)] = val;
      }
    }
  }
}

// ---------------- split scan: 2 blocks per batch, 128 blocks (chunk 0) ------
// Block bid: batch b=bid&63, half hb=bid>>6 owns units [128hb,128hb+128).
// Thread tid: local unit u=tid>>2, gate g=tid&3, col = 4*(128hb+u)+g, K=256.
// Per-thread weights 128 h2: 96 in regs (+~30 working = fits the 128-arch
// budget -> NO accvgpr tax) + 32 h2 LDS tail. Per-step cross-block h exchange:
// publish 128 packed (tag<<16|h) words (32-bit self-validating, relaxed
// agent-scope atomics, slot = t&1; pub memset to 0 before launch so graph
// replays can't see stale tags). Partner poll by threads 0..127.
__global__ void __launch_bounds__(512, 2) lstm_split_k(
    const f16* __restrict__ Wq, const f16* __restrict__ xp,
    f16* __restrict__ hout, float* __restrict__ c_state, f16* __restrict__ h_state,
    unsigned int* __restrict__ pub, int TC, int first)
{
  const int bid = blockIdx.x;
  const int b = bid & 63, hb = bid >> 6;
  const int tid = threadIdx.x;
  const int u = tid >> 2, g = tid & 3;
  const int gu = hb * 128 + u;
  __shared__ __align__(16) h2 hbuf[2][128];   // full h_t (256 f16), dbuf
  __shared__ uint4 wt[10][512];               // rows 0..7 used; 80 KB pads LDS
                                              // past 80KB -> 1 block/CU

  h2 w[96];
  {
    const uint4* p4 = (const uint4*)(Wq + (long)(hb * 512 + tid) * 256);
#pragma unroll
    for (int i = 0; i < 24; ++i) {
      uint4 v = p4[i];
      w[4 * i + 0] = bch2(v.x); w[4 * i + 1] = bch2(v.y);
      w[4 * i + 2] = bch2(v.z); w[4 * i + 3] = bch2(v.w);
    }
#pragma unroll
    for (int r = 0; r < 8; ++r) wt[r][tid] = p4[24 + r];
  }

  float c = first ? 0.f : c_state[b * Hh + gu];   // all 4 quad lanes hold c
  if (tid < 128) {
    h2 hz = {(f16)0.f, (f16)0.f};
    hbuf[0][tid] = first ? hz : ((const h2*)h_state)[b * 128 + tid];
  }
  __syncthreads();

  const float sgn = (g == 2) ? 2.0f : -1.0f;
  const int xcol = hb * 512 + tid;                // quad-gate xp: = 4*gu+g
  const f16* xptr = xp + (long)b * TC * G4 + xcol;
  const f16* xend = xptr + (long)(TC - 1) * G4;
  f16 xc = *xptr;
  unsigned int* pub_own = pub + ((b * 2 + hb) * 2) * 128;
  unsigned int* pub_par = pub + ((b * 2 + (hb ^ 1)) * 2) * 128;
  int p = 0;
  for (int t = 0; t < TC; ++t) {
    const f16* xnp = (xptr == xend) ? xptr : xptr + G4;
    f16 xn = *xnp;

    float a0 = (float)xc, b0 = 0.f;
    const uint4* hb4 = (const uint4*)&hbuf[p][0];
#pragma unroll
    for (int i = 0; i < 24; ++i) {                // register head, k<192
      uint4 hv = hb4[i];
      a0 = fdot2f(w[4 * i + 0], bch2(hv.x), a0);
      b0 = fdot2f(w[4 * i + 1], bch2(hv.y), b0);
      a0 = fdot2f(w[4 * i + 2], bch2(hv.z), a0);
      b0 = fdot2f(w[4 * i + 3], bch2(hv.w), b0);
    }
#pragma unroll
    for (int r = 0; r < 8; ++r) {                 // LDS tail, k in [192,256)
      uint4 hv = hb4[24 + r];
      uint4 wv = wt[r][tid];
      a0 = fdot2f(bch2(wv.x), bch2(hv.x), a0);
      b0 = fdot2f(bch2(wv.y), bch2(hv.y), b0);
      a0 = fdot2f(bch2(wv.z), bch2(hv.z), a0);
      b0 = fdot2f(bch2(wv.w), bch2(hv.w), b0);
    }
    float A = a0 + b0;

    float e = __expf(sgn * A);
    float r0 = __builtin_amdgcn_rcpf(1.0f + e);
    float act = (g == 2) ? 1.0f - 2.0f * r0 : r0;

    float ai = qb<0x00>(act), af = qb<0x55>(act);
    float ag = qb<0xAA>(act), ao = qb<0xFF>(act);
    c = af * c + ai * ag;                          // redundant in all 4 lanes
    float hval = ao * tanhf_(c);

    f16 hh = (f16)hval;
    if (g == 0) {
      ((f16*)&hbuf[p ^ 1][0])[gu] = hh;            // own half, local
      unsigned word = ((unsigned)(t + 1) << 16) |
                      (unsigned)__builtin_bit_cast(unsigned short, hh);
      __hip_atomic_store(&pub_own[(t & 1) * 128 + u], word,
                         __ATOMIC_RELAXED, __HIP_MEMORY_SCOPE_AGENT);
      hout[((long)b * TC + t) * Hh + gu] = hh;
    }
    if (tid < 128) {                               // poll partner half
      const unsigned want = (unsigned)(t + 1);
      unsigned v;
      while (((v = __hip_atomic_load(&pub_par[(t & 1) * 128 + tid],
                                     __ATOMIC_RELAXED,
                                     __HIP_MEMORY_SCOPE_AGENT)) >> 16) != want)
        __builtin_amdgcn_s_sleep(2);
      ((f16*)&hbuf[p ^ 1][0])[(hb ^ 1) * 128 + tid] =
          __builtin_bit_cast(f16, (unsigned short)(v & 0xffffu));
    }
    __syncthreads();
    p ^= 1;
    xc = xn;
    xptr = xnp;
  }
  if (g == 0) c_state[b * Hh + gu] = c;
  if (tid < 128 && hb == 0)
    ((h2*)h_state)[b * 128 + tid] = hbuf[p][tid];
}

// ---------------- v512 scan (control, proven ~1450 us; chunk 1) -------------
__global__ void __launch_bounds__(512, 2) lstm512_k(
    const f16* __restrict__ WhT2, const f16* __restrict__ xp,
    f16* __restrict__ hout, float* __restrict__ c_state, f16* __restrict__ h_state,
    int TC, int first)
{
  const int b = blockIdx.x, tid = threadIdx.x;
  const int j = tid >> 1, odd = tid & 1;
  __shared__ __align__(16) h2 hbuf[2][128];
  __shared__ uint4 wt[16][512];

  h2 w[192];
  {
    const uint4* p4 = (const uint4*)(WhT2 + (long)tid * 512);
#pragma unroll
    for (int u = 0; u < 48; ++u) {
      uint4 v = p4[u];
      w[4 * u + 0] = bch2(v.x); w[4 * u + 1] = bch2(v.y);
      w[4 * u + 2] = bch2(v.z); w[4 * u + 3] = bch2(v.w);
    }
#pragma unroll
    for (int gg = 0; gg < 16; ++gg) wt[gg][tid] = p4[48 + gg];
  }

  float c = first ? 0.f : c_state[b * Hh + j];
  if (tid < 128) {
    h2 hz = {(f16)0.f, (f16)0.f};
    hbuf[0][tid] = first ? hz : ((const h2*)h_state)[b * 128 + tid];
  }
  __syncthreads();

  const float sgn0 = odd ? 2.0f : -1.0f;
  const f16* xptr = xp + (long)b * TC * G4 + 2 * tid;
  const f16* xend = xptr + (long)(TC - 1) * G4;
  h2 xv = *(const h2*)xptr;
  int p = 0;
  for (int t = 0; t < TC; ++t) {
    const f16* xnp = (xptr == xend) ? xptr : xptr + G4;
    h2 xn = *(const h2*)xnp;

    float a0 = (float)xv[0], b0 = 0.f, a1 = (float)xv[1], b1 = 0.f;
    const uint4* hb4 = (const uint4*)&hbuf[p][0];
#pragma unroll
    for (int i = 0; i < 24; ++i) {
      uint4 hv = hb4[i];
      a0 = fdot2f(w[4 * i + 0], bch2(hv.x), a0);
      b0 = fdot2f(w[4 * i + 1], bch2(hv.y), b0);
      a0 = fdot2f(w[4 * i + 2], bch2(hv.z), a0);
      b0 = fdot2f(w[4 * i + 3], bch2(hv.w), b0);
      a1 = fdot2f(w[96 + 4 * i + 0], bch2(hv.x), a1);
      b1 = fdot2f(w[96 + 4 * i + 1], bch2(hv.y), b1);
      a1 = fdot2f(w[96 + 4 * i + 2], bch2(hv.z), a1);
      b1 = fdot2f(w[96 + 4 * i + 3], bch2(hv.w), b1);
    }
#pragma unroll
    for (int gg = 0; gg < 8; ++gg) {
      uint4 hv = hb4[24 + gg];
      uint4 wa = wt[gg][tid];
      uint4 wb = wt[8 + gg][tid];
      a0 = fdot2f(bch2(wa.x), bch2(hv.x), a0);
      b0 = fdot2f(bch2(wa.y), bch2(hv.y), b0);
      a0 = fdot2f(bch2(wa.z), bch2(hv.z), a0);
      b0 = fdot2f(bch2(wa.w), bch2(hv.w), b0);
      a1 = fdot2f(bch2(wb.x), bch2(hv.x), a1);
      b1 = fdot2f(bch2(wb.y), bch2(hv.y), b1);
      a1 = fdot2f(bch2(wb.z), bch2(hv.z), a1);
      b1 = fdot2f(bch2(wb.w), bch2(hv.w), b1);
    }
    float A0 = a0 + b0, A1 = a1 + b1;

    float e0 = __expf(sgn0 * A0);
    float r0 = __builtin_amdgcn_rcpf(1.0f + e0);
    float act0 = odd ? 1.0f - 2.0f * r0 : r0;
    float e1 = __expf(-A1);
    float act1 = __builtin_amdgcn_rcpf(1.0f + e1);

    float px0 = qb<0xB1>(act0), px1 = qb<0xB1>(act1);
    float ai = odd ? px0 : act0;
    float af = odd ? px1 : act1;
    float ag = odd ? act0 : px0;
    float ao = odd ? act1 : px1;
    c = af * c + ai * ag;
    float hval = ao * tanhf_(c);
    if (!odd) {
      f16 hh = (f16)hval;
      ((f16*)&hbuf[p ^ 1][0])[j] = hh;
      hout[((long)b * TC + t) * Hh + j] = hh;
    }
    __syncthreads();
    p ^= 1;
    xv = xn;
    xptr = xnp;
  }
  if (!odd) c_state[b * Hh + j] = c;
  if (tid < 128) ((h2*)h_state)[b * 128 + tid] = hbuf[p][tid];
}

// ---------------- host ----------------
extern "C" void kernel_launch(void* const* d_in, const int* in_sizes, int n_in,
                              void* d_out, int out_size, void* d_ws, size_t ws_size,
                              hipStream_t stream)
{
  const float* x  = (const float*)d_in[0];
  const float* Wi = (const float*)d_in[1];
  const float* Wh = (const float*)d_in[2];
  const float* bh = (const float*)d_in[3];
  const float* W1 = (const float*)d_in[4];
  const float* b1 = (const float*)d_in[5];
  const float* W2 = (const float*)d_in[6];
  const float* b2 = (const float*)d_in[7];
  float* out = (float*)d_out;

  char* ws = (char*)d_ws;
  size_t off = 0;
  auto alloc = [&](size_t bytes) -> char* {
    char* p = ws + off;
    off = (off + bytes + 255) & ~(size_t)255;
    return p;
  };
  f16* x16    = (f16*)alloc((size_t)Bb * Tt * Xx * 2);
  f16* wi16p  = (f16*)alloc((size_t)Xx * G4 * 2);
  float* bhp  = (float*)alloc((size_t)G4 * 4);
  f16* whT2   = (f16*)alloc((size_t)G4 * Hh * 2);
  f16* whQ    = (f16*)alloc((size_t)G4 * Hh * 2);
  f16* w116   = (f16*)alloc((size_t)Hh * Hh * 2);
  f16* w216   = (f16*)alloc((size_t)Hh * Z2 * 2);
  float* cst  = (float*)alloc((size_t)Bb * Hh * 4);
  f16* hst    = (f16*)alloc((size_t)Bb * Hh * 2);
  const size_t PUBSZ = (size_t)Bb * 2 * 2 * 128 * 4;  // 128 KB
  unsigned int* pub = (unsigned int*)alloc(PUBSZ);

  int tc = 1024;  // 2 chunks: chunk0 = split experiment, chunk1 = control
  while (tc > 32) {
    size_t need = (size_t)Bb * tc * G4 * 2 + (size_t)Bb * tc * Hh * 2;
    if (off + need <= ws_size) break;
    tc >>= 1;
  }
  int tcsh = __builtin_ctz((unsigned)tc);
  f16* xp16 = (f16*)alloc((size_t)Bb * tc * G4 * 2);
  f16* h16  = (f16*)alloc((size_t)Bb * tc * Hh * 2);
  f16* hid16 = xp16;  // head hidden aliases xp (xp fully consumed by the scan)

  cast_f16_k<<<(Bb * Tt * Xx) / 1024, 256, 0, stream>>>(x, x16, Bb * Tt * Xx);
  cast_wiP_k<<<(Xx * G4) / 256, 256, 0, stream>>>(Wi, wi16p);
  cast_bhp_k<<<4, 256, 0, stream>>>(bh, bhp);
  cast_f16_k<<<(Hh * Hh) / 1024, 256, 0, stream>>>(W1, w116, Hh * Hh);
  cast_f16_k<<<(Hh * Z2) / 1024, 256, 0, stream>>>(W2, w216, Hh * Z2);
  cast_whT2_k<<<(Hh * G4) / 256, 256, 0, stream>>>(Wh, whT2);
  cast_whQ_k<<<(Hh * G4) / 256, 256, 0, stream>>>(Wh, whQ);

  float* mu = out;
  float* ls = out + (size_t)Bb * Tt * 64;

  int ci = 0;
  for (int t0 = 0; t0 < Tt; t0 += tc, ++ci) {
    dim3 gx(Bb * tc / 64, G4 / 64);
    gemm_f16_k<<<gx, 256, 0, stream>>>(x16, wi16p, bhp, xp16, nullptr, nullptr,
                                       G4, Xx, tcsh, Tt, t0, 0, 0, 0);
    if (ci == 0) {
      hipMemsetAsync(pub, 0, PUBSZ, stream);
      lstm_split_k<<<128, 512, 0, stream>>>(whQ, xp16, h16, cst, hst, pub, tc,
                                            (t0 == 0) ? 1 : 0);
    } else {
      lstm512_k<<<Bb, 512, 0, stream>>>(whT2, xp16, h16, cst, hst, tc,
                                        (t0 == 0) ? 1 : 0);
    }
    dim3 g1g(Bb * tc / 64, Hh / 64);
    gemm_f16_k<<<g1g, 256, 0, stream>>>(h16, w116, b1, hid16, nullptr, nullptr,
                                        Hh, Hh, 30, 0, 0, 1, 0, 0);
    dim3 g2g(Bb * tc / 64, Z2 / 64);
    gemm_f16_k<<<g2g, 256, 0, stream>>>(hid16, w216, b2, nullptr, mu, ls,
                                        Z2, Hh, 30, 0, 0, 2, t0, tcsh);
  }
}